// Round 6
// baseline (379.011 us; speedup 1.0000x reference)
//
#include <hip/hip_runtime.h>

#define BB 1024
#define TT 1024
#define KQ 15
#define KT 20
#define NDOF 7
#define HT 512              // half t-range per block

// Output layout (flat float offsets, in reference return order)
#define OFF_MODEL 0
#define OFF_QDL   1
#define OFF_QDDL  (1 + BB*NDOF)
#define OFF_QDDDL (1 + 2*BB*NDOF)
#define OFF_TQL   (1 + 3*BB*NDOF)
#define OFF_Q     (1 + 4*BB*NDOF)
#define OFF_QD    (OFF_Q    + (size_t)BB*TT*NDOF)
#define OFF_QDD   (OFF_QD   + (size_t)BB*TT*NDOF)
#define OFF_QDDD  (OFF_QDD  + (size_t)BB*TT*NDOF)
#define OFF_TQ    (OFF_QDDD + (size_t)BB*TT*NDOF)
#define OFF_T     (OFF_TQ   + (size_t)BB*TT*NDOF)
#define OFF_TCUM  (OFF_T    + (size_t)BB)
#define OFF_DT    (OFF_TCUM + (size_t)BB*TT)

__device__ __forceinline__ float hub(float v, float lim) {
    // huber(relu(|v| - lim)), delta = 1.0
    float x = fabsf(v) - lim;
    x = fmaxf(x, 0.0f);
    return (x < 1.0f) ? 0.5f * x * x : (x - 0.5f);
}

// 16B store at a 4B-aligned address (verified on this harness)
__device__ __forceinline__ void st4(float* p, float x0, float x1, float x2, float x3) {
    float v[4] = {x0, x1, x2, x3};
    __builtin_memcpy(p, v, 16);
}

// 8B store at a 4B-aligned address
__device__ __forceinline__ void st2(float* p, float x0, float x1) {
    float v[2] = {x0, x1};
    __builtin_memcpy(p, v, 8);
}

// Split + line-covering copy-out:
// 2048 blocks (2 per b, each owns 512 t's), launch_bounds(256,8) -> 8 blocks/CU.
// R5 lesson (counters): scattered 28B st7 stores at high occupancy blew the
// per-XCD L2 dirty-line working set -> partial-line evictions -> WRITE 377MB /
// FETCH 136MB (ideal ~155/25). Fix: stage each output array per round in LDS
// and store as wave-contiguous dwordx4 runs (R0's copy-out measured the ideal
// 153MB WRITE at even higher concurrency). Scan/atomic logic from R5 verbatim.
__global__ __launch_bounds__(256, 8) void feas_fused(
    const float* __restrict__ q_cps, const float* __restrict__ t_cps,
    const float* __restrict__ Nb,  const float* __restrict__ dNb,
    const float* __restrict__ ddNb, const float* __restrict__ dddNb,
    const float* __restrict__ Ntb, const float* __restrict__ dNtb,
    const float* __restrict__ ddNtb,
    const float* __restrict__ qd_lim, const float* __restrict__ qdd_lim,
    const float* __restrict__ qddd_lim,
    float* __restrict__ out)
{
    const int bid  = blockIdx.x;
    const int b    = bid >> 1;
    const int h    = bid & 1;           // which half of the t-range
    const int tid  = threadIdx.x;
    const int lane = tid & 63;
    const int w    = tid >> 6;

    __shared__ __align__(16) float stage[256 * NDOF];  // 7 KB transpose buffer
    __shared__ __align__(16) float sdt[HT];            // this half's dt values
    __shared__ float wsum[4];                          // per-wave scan totals
    __shared__ float osw[4];                           // lower-half dt sum partials (h==1)
    __shared__ float lossw[4][21];                     // per-wave loss partials

    // whole block shares one b -> wave-uniform -> scalar loads
    const float* cps = q_cps + (size_t)b * (KQ * NDOF);
    const float* tcp = t_cps + (size_t)b * KT;

    float tcr[KT];                      // uniform -> lives in SGPRs
    #pragma unroll
    for (int k = 0; k < KT; ++k) tcr[k] = tcp[k];

    float ls[21];
    #pragma unroll
    for (int j = 0; j < 21; ++j) ls[j] = 0.f;

    const int t0 = h * HT;

    // stage ARR (NDOF floats/thread) -> LDS -> wave-contiguous dwordx4 stores.
    // 1792 floats/round = 448 float4: thread does float4 #tid and #(256+tid<448).
#define COPYOUT(ARR, OFFBASE, GB0)                                              \
    do {                                                                        \
        __syncthreads();   /* previous array's LDS reads complete */            \
        _Pragma("unroll")                                                       \
        for (int d = 0; d < NDOF; ++d) stage[tid * NDOF + d] = ARR[d];          \
        __syncthreads();                                                        \
        float* gdst = out + (OFFBASE) + (GB0);                                  \
        const float4 v0 = *(const float4*)(stage + 4 * tid);                    \
        st4(gdst + 4 * tid, v0.x, v0.y, v0.z, v0.w);                            \
        if (tid < 192) {                                                        \
            const float4 v1 = *(const float4*)(stage + 1024 + 4 * tid);         \
            st4(gdst + 1024 + 4 * tid, v1.x, v1.y, v1.z, v1.w);                 \
        }                                                                       \
    } while (0)

    #pragma unroll 1
    for (int r = 0; r < HT / 256; ++r) {
        const int tl = r * 256 + tid;       // local index within half
        const int t  = t0 + tl;             // global t

        // ---- time-spline: 3 x 20 FMA ----
        const float* pt0 = Ntb   + (size_t)t * KT;
        const float* pt1 = dNtb  + (size_t)t * KT;
        const float* pt2 = ddNtb + (size_t)t * KT;
        float dtau = 0.f, ddtau = 0.f, dddtau = 0.f;
        #pragma unroll
        for (int k = 0; k < KT; ++k) {
            const float tc = tcr[k];
            dtau   = fmaf(pt0[k], tc, dtau);
            ddtau  = fmaf(pt1[k], tc, ddtau);
            dddtau = fmaf(pt2[k], tc, dddtau);
        }

        // ---- q-spline: 4 x 15 x 7 FMA ----
        const float* p0 = Nb    + (size_t)t * KQ;
        const float* p1 = dNb   + (size_t)t * KQ;
        const float* p2 = ddNb  + (size_t)t * KQ;
        const float* p3 = dddNb + (size_t)t * KQ;
        float aq[NDOF], a1[NDOF], a2[NDOF], a3[NDOF];
        #pragma unroll
        for (int d = 0; d < NDOF; ++d) { aq[d] = 0.f; a1[d] = 0.f; a2[d] = 0.f; a3[d] = 0.f; }
        #pragma unroll
        for (int k = 0; k < KQ; ++k) {
            const float n0 = p0[k], n1 = p1[k], n2 = p2[k], n3 = p3[k];
            #pragma unroll
            for (int d = 0; d < NDOF; ++d) {
                const float cc = cps[k * NDOF + d];   // uniform -> s_load
                aq[d] = fmaf(n0, cc, aq[d]);
                a1[d] = fmaf(n1, cc, a1[d]);
                a2[d] = fmaf(n2, cc, a2[d]);
                a3[d] = fmaf(n3, cc, a3[d]);
            }
        }

        const float dtau2 = dtau * dtau;
        const float dtau3 = dtau2 * dtau;
        const float dtv   = 1.0f / (dtau * (float)TT);

        float qd[NDOF], qdd[NDOF], qddd[NDOF];
        #pragma unroll
        for (int d = 0; d < NDOF; ++d) {
            qd[d]   = a1[d] * dtau;
            qdd[d]  = a2[d] * dtau2 + ddtau * a1[d] * dtau;
            qddd[d] = a3[d] * dtau3 + 3.0f * a2[d] * ddtau * dtau2
                    + a1[d] * dtau2 * dddtau + a1[d] * ddtau * ddtau * dtau;
        }

        #pragma unroll
        for (int d = 0; d < NDOF; ++d) {
            ls[d]          += hub(qd[d],   qd_lim[d])   * dtv;
            ls[NDOF + d]   += hub(qdd[d],  qdd_lim[d])  * dtv;
            ls[2*NDOF + d] += hub(qddd[d], qddd_lim[d]) * dtv;
        }

        sdt[tl] = dtv;
        out[OFF_DT + (size_t)b * TT + t] = dtv;   // coalesced dword, line-covering per wave

        // ---- line-covering copy-out via LDS transpose ----
        const size_t gb0 = (size_t)b * (TT * NDOF) + (size_t)(t0 + r * 256) * NDOF;
        COPYOUT(aq,   OFF_Q,    gb0);
        COPYOUT(qd,   OFF_QD,   gb0);
        COPYOUT(qdd,  OFF_QDD,  gb0);
        COPYOUT(qddd, OFF_QDDD, gb0);
        // torque == 0: direct float4 zero stores (contiguous -> line-covering)
        {
            float* z = out + OFF_TQ + gb0;
            st4(z + 4 * tid, 0.f, 0.f, 0.f, 0.f);
            if (tid < 192) st4(z + 1024 + 4 * tid, 0.f, 0.f, 0.f, 0.f);
        }
    }
#undef COPYOUT

    // ---- upper block: redundant lower-half dtau -> cumsum base (no cross-block sync) ----
    float osum = 0.f;
    if (h) {
        #pragma unroll 1
        for (int r = 0; r < HT / 256; ++r) {
            const int t = r * 256 + tid;          // lower-half t
            const float* pt0 = Ntb + (size_t)t * KT;
            float dtau = 0.f;
            #pragma unroll
            for (int k = 0; k < KT; ++k) dtau = fmaf(pt0[k], tcr[k], dtau);
            osum += 1.0f / (dtau * (float)TT);
        }
        #pragma unroll
        for (int off = 32; off > 0; off >>= 1) osum += __shfl_down(osum, off);
        if (lane == 0) osw[w] = osum;
    }
    __syncthreads();   // sdt + osw visible

    // ---- in-block inclusive scan of this half's 512 dt (2 contiguous per thread) ----
    const int e = 2 * tid;
    const float2 dv = *(const float2*)(sdt + e);   // 8B-aligned LDS read
    const float c0 = dv.x;
    const float c1 = c0 + dv.y;
    float s = c1;
    #pragma unroll
    for (int off = 1; off < 64; off <<= 1) {
        const float u = __shfl_up(s, off);
        if (lane >= off) s += u;
    }
    if (lane == 63) wsum[w] = s;   // inclusive wave total (128 elems)

    // ---- wave loss reduce (register-only) ----
    #pragma unroll
    for (int j = 0; j < 21; ++j) {
        float v = ls[j];
        #pragma unroll
        for (int off = 32; off > 0; off >>= 1) v += __shfl_down(v, off);
        ls[j] = v;   // valid at lane 0
    }
    if (lane == 0) {
        #pragma unroll
        for (int j = 0; j < 21; ++j) lossw[w][j] = ls[j];
    }

    __syncthreads();   // wsum + lossw visible

    float base = 0.f;
    if (h) base = osw[0] + osw[1] + osw[2] + osw[3];
    float woff = 0.f;
    #pragma unroll
    for (int i = 0; i < 4; ++i) if (i < w) woff += wsum[i];
    const float pre = base + woff + (s - c1);   // exclusive prefix before element e
    st2(out + OFF_TCUM + (size_t)b * TT + t0 + e, pre + c0, pre + c1);

    if (h && tid == 0)
        out[OFF_T + b] = base + wsum[0] + wsum[1] + wsum[2] + wsum[3];

    // ---- losses: relaxed HW atomics onto memset-zeroed region (2 blocks per b) ----
    if (tid < 21) {
        const float acc = lossw[0][tid] + lossw[1][tid] + lossw[2][tid] + lossw[3][tid];
        const int which = tid / NDOF, d = tid - which * NDOF;
        const size_t o = (which == 0) ? (size_t)OFF_QDL
                       : (which == 1) ? (size_t)OFF_QDDL : (size_t)OFF_QDDDL;
        unsafeAtomicAdd(out + o + (size_t)b * NDOF + d, acc);
    }
    // OFF_TQL region zeroed by host memset (torque == 0)
    if (tid == 0) {
        float p = 0.f;
        #pragma unroll
        for (int i = 0; i < 4; ++i) {
            #pragma unroll
            for (int j = 0; j < 21; ++j) p += lossw[i][j];
        }
        unsafeAtomicAdd(out + OFF_MODEL, p);   // global_atomic_add_f32, no fence
    }
}

extern "C" void kernel_launch(void* const* d_in, const int* in_sizes, int n_in,
                              void* d_out, int out_size, void* d_ws, size_t ws_size,
                              hipStream_t stream) {
    const float* q_cps    = (const float*)d_in[0];
    const float* t_cps    = (const float*)d_in[1];
    const float* Nb       = (const float*)d_in[2];
    const float* dNb      = (const float*)d_in[3];
    const float* ddNb     = (const float*)d_in[4];
    const float* dddNb    = (const float*)d_in[5];
    const float* Ntb      = (const float*)d_in[6];
    const float* dNtb     = (const float*)d_in[7];
    const float* ddNtb    = (const float*)d_in[8];
    const float* qd_lim   = (const float*)d_in[9];
    const float* qdd_lim  = (const float*)d_in[10];
    const float* qddd_lim = (const float*)d_in[11];
    // d_in[12] = torque_limits — unused (torque is identically zero)
    float* out = (float*)d_out;

    // zero model_loss + all four per-b loss blocks (atomic accumulation targets
    // + torque-loss zeros) in one stream-ordered memset: floats [0, 1+4*BB*NDOF)
    hipMemsetAsync(out, 0, (size_t)(1 + 4 * BB * NDOF) * sizeof(float), stream);

    feas_fused<<<dim3(2 * BB), dim3(256), 0, stream>>>(
        q_cps, t_cps, Nb, dNb, ddNb, dddNb, Ntb, dNtb, ddNtb,
        qd_lim, qdd_lim, qddd_lim, out);
}

// Round 7
// 251.475 us; speedup vs baseline: 1.5072x; 1.5072x over previous
//
#include <hip/hip_runtime.h>

#define BB 1024
#define TT 1024
#define KQ 15
#define KT 20
#define NDOF 7

// Output layout (flat float offsets, in reference return order)
#define OFF_MODEL 0
#define OFF_QDL   1
#define OFF_QDDL  (1 + BB*NDOF)
#define OFF_QDDDL (1 + 2*BB*NDOF)
#define OFF_TQL   (1 + 3*BB*NDOF)
#define OFF_Q     (1 + 4*BB*NDOF)
#define OFF_QD    (OFF_Q    + (size_t)BB*TT*NDOF)
#define OFF_QDD   (OFF_QD   + (size_t)BB*TT*NDOF)
#define OFF_QDDD  (OFF_QDD  + (size_t)BB*TT*NDOF)
#define OFF_TQ    (OFF_QDDD + (size_t)BB*TT*NDOF)
#define OFF_T     (OFF_TQ   + (size_t)BB*TT*NDOF)
#define OFF_TCUM  (OFF_T    + (size_t)BB)
#define OFF_DT    (OFF_TCUM + (size_t)BB*TT)

__device__ __forceinline__ float hub(float v, float lim) {
    // huber(relu(|v| - lim)), delta = 1.0
    float x = fabsf(v) - lim;
    x = fmaxf(x, 0.0f);
    return (x < 1.0f) ? 0.5f * x * x : (x - 0.5f);
}

// 4B-aligned vector types (output arrays are offset by 1 float -> addr = 4 mod 16;
// gfx950 global_store_dwordx4 only needs dword alignment; proven in R2-R4 via memcpy)
typedef float vf4 __attribute__((ext_vector_type(4)));
typedef vf4  vf4u __attribute__((aligned(4)));
typedef float vf2 __attribute__((ext_vector_type(2)));
typedef vf2  vf2u __attribute__((aligned(4)));

// Nontemporal 28B store (7 floats): dwordx4 + dwordx2 + dword, all with nt policy.
// NT keeps the 155MB output stream from evicting the L2-resident basis matrices.
__device__ __forceinline__ void st7nt(float* p, const float* a) {
    vf4 v4 = {a[0], a[1], a[2], a[3]};
    __builtin_nontemporal_store(v4, (vf4u*)p);
    vf2 v2 = {a[4], a[5]};
    __builtin_nontemporal_store(v2, (vf2u*)(p + 4));
    __builtin_nontemporal_store(a[6], p + 6);
}

__device__ __forceinline__ void st4nt(float* p, float x0, float x1, float x2, float x3) {
    vf4 v4 = {x0, x1, x2, x3};
    __builtin_nontemporal_store(v4, (vf4u*)p);
}

// R4 structure (measured best: kernel ~90us, WRITE 179MB / FETCH 24MB) + NT stores.
// R5/R6 lesson (counters): doubling concurrency to 2048 blocks blew write-combining
// in the 4MB/XCD L2 -> FETCH+WRITE exploded (136/377 -> 222/545 MB) regardless of
// store contiguity. Stay at 1024 blocks, 4 blocks/CU.
// One block per b; 256 threads; thread handles t = r*256 + tid for r in [0,4).
__global__ __launch_bounds__(256, 4) void feas_fused(
    const float* __restrict__ q_cps, const float* __restrict__ t_cps,
    const float* __restrict__ Nb,  const float* __restrict__ dNb,
    const float* __restrict__ ddNb, const float* __restrict__ dddNb,
    const float* __restrict__ Ntb, const float* __restrict__ dNtb,
    const float* __restrict__ ddNtb,
    const float* __restrict__ qd_lim, const float* __restrict__ qdd_lim,
    const float* __restrict__ qddd_lim,
    float* __restrict__ out)
{
    const int b    = blockIdx.x;
    const int tid  = threadIdx.x;
    const int lane = tid & 63;
    const int w    = tid >> 6;

    __shared__ __align__(16) float sdt[TT];   // dt row for the in-block scan
    __shared__ float wsum[4];                 // per-wave scan totals
    __shared__ float lossw[4][21];            // per-wave loss partials

    // whole block shares one b -> wave-uniform -> scalar loads
    const float* cps = q_cps + (size_t)b * (KQ * NDOF);
    const float* tcp = t_cps + (size_t)b * KT;

    // hoist time-spline control points into registers once
    float tcr[KT];
    #pragma unroll
    for (int k = 0; k < KT; ++k) tcr[k] = tcp[k];

    float ls[21];
    #pragma unroll
    for (int j = 0; j < 21; ++j) ls[j] = 0.f;

    // keep the round loop rolled: body is large; 4x unroll would blow I-cache
    #pragma unroll 1
    for (int r = 0; r < TT / 256; ++r) {
        const int t = r * 256 + tid;

        // ---- time-spline: 3 x 20 FMA, rows read straight from global (L2-hot) ----
        const float* pt0 = Ntb   + (size_t)t * KT;
        const float* pt1 = dNtb  + (size_t)t * KT;
        const float* pt2 = ddNtb + (size_t)t * KT;
        float dtau = 0.f, ddtau = 0.f, dddtau = 0.f;
        #pragma unroll
        for (int k = 0; k < KT; ++k) {
            const float tc = tcr[k];
            dtau   = fmaf(pt0[k], tc, dtau);
            ddtau  = fmaf(pt1[k], tc, ddtau);
            dddtau = fmaf(pt2[k], tc, dddtau);
        }

        // ---- q-spline: 4 x 15 x 7 FMA ----
        const float* p0 = Nb    + (size_t)t * KQ;
        const float* p1 = dNb   + (size_t)t * KQ;
        const float* p2 = ddNb  + (size_t)t * KQ;
        const float* p3 = dddNb + (size_t)t * KQ;
        float aq[NDOF], a1[NDOF], a2[NDOF], a3[NDOF];
        #pragma unroll
        for (int d = 0; d < NDOF; ++d) { aq[d] = 0.f; a1[d] = 0.f; a2[d] = 0.f; a3[d] = 0.f; }
        #pragma unroll
        for (int k = 0; k < KQ; ++k) {
            const float n0 = p0[k], n1 = p1[k], n2 = p2[k], n3 = p3[k];
            #pragma unroll
            for (int d = 0; d < NDOF; ++d) {
                const float cc = cps[k * NDOF + d];   // uniform -> s_load
                aq[d] = fmaf(n0, cc, aq[d]);
                a1[d] = fmaf(n1, cc, a1[d]);
                a2[d] = fmaf(n2, cc, a2[d]);
                a3[d] = fmaf(n3, cc, a3[d]);
            }
        }

        const float dtau2 = dtau * dtau;
        const float dtau3 = dtau2 * dtau;
        const float dtv   = 1.0f / (dtau * (float)TT);

        float qd[NDOF], qdd[NDOF], qddd[NDOF];
        #pragma unroll
        for (int d = 0; d < NDOF; ++d) {
            qd[d]   = a1[d] * dtau;
            qdd[d]  = a2[d] * dtau2 + ddtau * a1[d] * dtau;
            qddd[d] = a3[d] * dtau3 + 3.0f * a2[d] * ddtau * dtau2
                    + a1[d] * dtau2 * dddtau + a1[d] * ddtau * ddtau * dtau;
        }

        // ---- loss partials accumulate in registers across rounds ----
        #pragma unroll
        for (int d = 0; d < NDOF; ++d) {
            ls[d]          += hub(qd[d],   qd_lim[d])   * dtv;
            ls[NDOF + d]   += hub(qdd[d],  qdd_lim[d])  * dtv;
            ls[2*NDOF + d] += hub(qddd[d], qddd_lim[d]) * dtv;
        }

        // ---- direct NT stores: per-lane 28B, wave covers a dense 1792B run ----
        const size_t gb = (size_t)b * (TT * NDOF) + (size_t)t * NDOF;
        st7nt(out + OFF_Q    + gb, aq);
        st7nt(out + OFF_QD   + gb, qd);
        st7nt(out + OFF_QDD  + gb, qdd);
        st7nt(out + OFF_QDDD + gb, qddd);
        {   // torque == 0: literal zero NT stores
            float* z = out + OFF_TQ + gb;
            st4nt(z, 0.f, 0.f, 0.f, 0.f);
            vf2 z2 = {0.f, 0.f};
            __builtin_nontemporal_store(z2, (vf2u*)(z + 4));
            __builtin_nontemporal_store(0.f, z + 6);
        }
        __builtin_nontemporal_store(dtv, out + OFF_DT + (size_t)b * TT + t);
        sdt[t] = dtv;
    }

    __syncthreads();

    // ---- in-block inclusive scan of sdt ----
    const int s4 = 4 * tid;
    const float4 dvv = *(const float4*)(sdt + s4);   // 16B-aligned LDS read
    const float c0 = dvv.x;
    const float c1 = c0 + dvv.y;
    const float c2 = c1 + dvv.z;
    const float c3 = c2 + dvv.w;
    float s = c3;
    #pragma unroll
    for (int off = 1; off < 64; off <<= 1) {
        const float u = __shfl_up(s, off);
        if (lane >= off) s += u;
    }
    if (lane == 63) wsum[w] = s;   // inclusive wave total

    // ---- wave loss reduce ----
    #pragma unroll
    for (int j = 0; j < 21; ++j) {
        float v = ls[j];
        #pragma unroll
        for (int off = 32; off > 0; off >>= 1) v += __shfl_down(v, off);
        ls[j] = v;   // valid at lane 0
    }
    if (lane == 0) {
        #pragma unroll
        for (int j = 0; j < 21; ++j) lossw[w][j] = ls[j];
    }

    __syncthreads();

    // cross-wave scan offset + t_cumsum stores (NT: written once, read by host only)
    float woff = 0.f;
    #pragma unroll
    for (int i = 0; i < 4; ++i) if (i < w) woff += wsum[i];
    const float excl = woff + (s - c3);   // exclusive prefix before this thread's 4 elems
    {
        vf4 tc4 = {c0 + excl, c1 + excl, c2 + excl, c3 + excl};
        __builtin_nontemporal_store(tc4, (vf4u*)(out + OFF_TCUM + (size_t)b * TT + s4));
    }

    // loss finalize (plain stores, tiny region)
    if (tid < 21) {
        const float acc = lossw[0][tid] + lossw[1][tid] + lossw[2][tid] + lossw[3][tid];
        const int which = tid / NDOF, d = tid - which * NDOF;
        const size_t o = (which == 0) ? (size_t)OFF_QDL
                       : (which == 1) ? (size_t)OFF_QDDL : (size_t)OFF_QDDDL;
        out[o + (size_t)b * NDOF + d] = acc;
    }
    if (tid < NDOF) out[OFF_TQL + (size_t)b * NDOF + tid] = 0.0f;  // torque == 0
    if (tid == 0) {
        out[OFF_T + b] = wsum[0] + wsum[1] + wsum[2] + wsum[3];
        // model_loss: one relaxed HW float atomic per block (no fence, no L2 flush)
        float p = 0.f;
        #pragma unroll
        for (int i = 0; i < 4; ++i) {
            #pragma unroll
            for (int j = 0; j < 21; ++j) p += lossw[i][j];
        }
        unsafeAtomicAdd(out + OFF_MODEL, p);   // global_atomic_add_f32, device-coherent
    }
}

extern "C" void kernel_launch(void* const* d_in, const int* in_sizes, int n_in,
                              void* d_out, int out_size, void* d_ws, size_t ws_size,
                              hipStream_t stream) {
    const float* q_cps    = (const float*)d_in[0];
    const float* t_cps    = (const float*)d_in[1];
    const float* Nb       = (const float*)d_in[2];
    const float* dNb      = (const float*)d_in[3];
    const float* ddNb     = (const float*)d_in[4];
    const float* dddNb    = (const float*)d_in[5];
    const float* Ntb      = (const float*)d_in[6];
    const float* dNtb     = (const float*)d_in[7];
    const float* ddNtb    = (const float*)d_in[8];
    const float* qd_lim   = (const float*)d_in[9];
    const float* qdd_lim  = (const float*)d_in[10];
    const float* qddd_lim = (const float*)d_in[11];
    // d_in[12] = torque_limits — unused (torque is identically zero)
    float* out = (float*)d_out;

    // zero the model_loss accumulator each iteration (stream-ordered, graph-legal)
    hipMemsetAsync(out + OFF_MODEL, 0, sizeof(float), stream);

    feas_fused<<<dim3(BB), dim3(256), 0, stream>>>(
        q_cps, t_cps, Nb, dNb, ddNb, dddNb, Ntb, dNtb, ddNtb,
        qd_lim, qdd_lim, qddd_lim, out);
}

// Round 8
// 237.111 us; speedup vs baseline: 1.5985x; 1.0606x over previous
//
#include <hip/hip_runtime.h>

#define BB 1024
#define TT 1024
#define KQ 15
#define KT 20
#define NDOF 7

// Output layout (flat float offsets, in reference return order)
#define OFF_MODEL 0
#define OFF_QDL   1
#define OFF_QDDL  (1 + BB*NDOF)
#define OFF_QDDDL (1 + 2*BB*NDOF)
#define OFF_TQL   (1 + 3*BB*NDOF)
#define OFF_Q     (1 + 4*BB*NDOF)
#define OFF_QD    (OFF_Q    + (size_t)BB*TT*NDOF)
#define OFF_QDD   (OFF_QD   + (size_t)BB*TT*NDOF)
#define OFF_QDDD  (OFF_QDD  + (size_t)BB*TT*NDOF)
#define OFF_TQ    (OFF_QDDD + (size_t)BB*TT*NDOF)
#define OFF_T     (OFF_TQ   + (size_t)BB*TT*NDOF)
#define OFF_TCUM  (OFF_T    + (size_t)BB)
#define OFF_DT    (OFF_TCUM + (size_t)BB*TT)

__device__ __forceinline__ float hub(float v, float lim) {
    // huber(relu(|v| - lim)), delta = 1.0
    float x = fabsf(v) - lim;
    x = fmaxf(x, 0.0f);
    return (x < 1.0f) ? 0.5f * x * x : (x - 0.5f);
}

// 16B store at a 4B-aligned address (verified on this harness, R2-R4)
__device__ __forceinline__ void st4(float* p, float x0, float x1, float x2, float x3) {
    float v[4] = {x0, x1, x2, x3};
    __builtin_memcpy(p, v, 16);
}

// 28B store (7 floats) at a 4B-aligned address: dwordx4 + dwordx2 + dword.
// PLAIN stores (through L2): R7 measured NT stores = sector-granular HBM drain,
// WRITE 179->215 MB and kernel 90->129us. L2 write-combining is our friend.
__device__ __forceinline__ void st7(float* p, const float* a) {
    float v4[4] = {a[0], a[1], a[2], a[3]};
    __builtin_memcpy(p, v4, 16);
    float v2[2] = {a[4], a[5]};
    __builtin_memcpy(p + 4, v2, 8);
    p[6] = a[6];
}

// R4 structure (measured best: kernel ~90us, WRITE 179MB / FETCH 24MB, 1024 blocks,
// 4 blocks/CU — R5/R6 showed higher concurrency blows L2 write-combining) with ONE
// load-side change: basis rows loaded as wide vectors via __builtin_memcpy
// (t-rows 80B 16B-aligned -> 5x dwordx4; q-rows 60B -> x4+x4+x4+x2+x1), cutting
// per-round VMEM instructions 120 -> ~35. k-loops fully unrolled -> rows stay in
// VGPRs. Phased: t-rows consumed before q-rows load (peak ~100 VGPR < 128 cap).
__global__ __launch_bounds__(256, 4) void feas_fused(
    const float* __restrict__ q_cps, const float* __restrict__ t_cps,
    const float* __restrict__ Nb,  const float* __restrict__ dNb,
    const float* __restrict__ ddNb, const float* __restrict__ dddNb,
    const float* __restrict__ Ntb, const float* __restrict__ dNtb,
    const float* __restrict__ ddNtb,
    const float* __restrict__ qd_lim, const float* __restrict__ qdd_lim,
    const float* __restrict__ qddd_lim,
    float* __restrict__ out)
{
    const int b    = blockIdx.x;
    const int tid  = threadIdx.x;
    const int lane = tid & 63;
    const int w    = tid >> 6;

    __shared__ __align__(16) float sdt[TT];   // dt row for the in-block scan
    __shared__ float wsum[4];                 // per-wave scan totals
    __shared__ float lossw[4][21];            // per-wave loss partials

    // whole block shares one b -> wave-uniform -> scalar loads
    const float* cps = q_cps + (size_t)b * (KQ * NDOF);
    const float* tcp = t_cps + (size_t)b * KT;

    // hoist time-spline control points into registers once
    float tcr[KT];
    #pragma unroll
    for (int k = 0; k < KT; ++k) tcr[k] = tcp[k];

    float ls[21];
    #pragma unroll
    for (int j = 0; j < 21; ++j) ls[j] = 0.f;

    // keep the round loop rolled: body is large; 4x unroll would blow I-cache
    #pragma unroll 1
    for (int r = 0; r < TT / 256; ++r) {
        const int t = r * 256 + tid;

        // ---- time-spline: 3 rows x 20 floats (80B, 16B-aligned) -> wide loads ----
        float dtau = 0.f, ddtau = 0.f, dddtau = 0.f;
        {
            float rt0[KT], rt1[KT], rt2[KT];
            __builtin_memcpy(rt0, Ntb   + (size_t)t * KT, KT * sizeof(float));
            __builtin_memcpy(rt1, dNtb  + (size_t)t * KT, KT * sizeof(float));
            __builtin_memcpy(rt2, ddNtb + (size_t)t * KT, KT * sizeof(float));
            #pragma unroll
            for (int k = 0; k < KT; ++k) {
                const float tc = tcr[k];
                dtau   = fmaf(rt0[k], tc, dtau);
                ddtau  = fmaf(rt1[k], tc, ddtau);
                dddtau = fmaf(rt2[k], tc, dddtau);
            }
        }   // rt* die here

        // ---- q-spline: 4 rows x 15 floats (60B) -> wide loads, then 15x7x4 FMA ----
        float aq[NDOF], a1[NDOF], a2[NDOF], a3[NDOF];
        #pragma unroll
        for (int d = 0; d < NDOF; ++d) { aq[d] = 0.f; a1[d] = 0.f; a2[d] = 0.f; a3[d] = 0.f; }
        {
            float r0[KQ], r1[KQ], r2[KQ], r3[KQ];
            __builtin_memcpy(r0, Nb    + (size_t)t * KQ, KQ * sizeof(float));
            __builtin_memcpy(r1, dNb   + (size_t)t * KQ, KQ * sizeof(float));
            __builtin_memcpy(r2, ddNb  + (size_t)t * KQ, KQ * sizeof(float));
            __builtin_memcpy(r3, dddNb + (size_t)t * KQ, KQ * sizeof(float));
            #pragma unroll
            for (int k = 0; k < KQ; ++k) {
                const float n0 = r0[k], n1 = r1[k], n2 = r2[k], n3 = r3[k];
                #pragma unroll
                for (int d = 0; d < NDOF; ++d) {
                    const float cc = cps[k * NDOF + d];   // uniform -> s_load
                    aq[d] = fmaf(n0, cc, aq[d]);
                    a1[d] = fmaf(n1, cc, a1[d]);
                    a2[d] = fmaf(n2, cc, a2[d]);
                    a3[d] = fmaf(n3, cc, a3[d]);
                }
            }
        }   // r* die here

        const float dtau2 = dtau * dtau;
        const float dtau3 = dtau2 * dtau;
        const float dtv   = 1.0f / (dtau * (float)TT);

        float qd[NDOF], qdd[NDOF], qddd[NDOF];
        #pragma unroll
        for (int d = 0; d < NDOF; ++d) {
            qd[d]   = a1[d] * dtau;
            qdd[d]  = a2[d] * dtau2 + ddtau * a1[d] * dtau;
            qddd[d] = a3[d] * dtau3 + 3.0f * a2[d] * ddtau * dtau2
                    + a1[d] * dtau2 * dddtau + a1[d] * ddtau * ddtau * dtau;
        }

        // ---- loss partials accumulate in registers across rounds ----
        #pragma unroll
        for (int d = 0; d < NDOF; ++d) {
            ls[d]          += hub(qd[d],   qd_lim[d])   * dtv;
            ls[NDOF + d]   += hub(qdd[d],  qdd_lim[d])  * dtv;
            ls[2*NDOF + d] += hub(qddd[d], qddd_lim[d]) * dtv;
        }

        // ---- direct plain stores: per-lane 28B, wave covers a dense 1792B run ----
        const size_t gb = (size_t)b * (TT * NDOF) + (size_t)t * NDOF;
        st7(out + OFF_Q    + gb, aq);
        st7(out + OFF_QD   + gb, qd);
        st7(out + OFF_QDD  + gb, qdd);
        st7(out + OFF_QDDD + gb, qddd);
        {   // torque == 0: literal zero stores
            float* z = out + OFF_TQ + gb;
            st4(z, 0.f, 0.f, 0.f, 0.f);
            float v2[2] = {0.f, 0.f};
            __builtin_memcpy(z + 4, v2, 8);
            z[6] = 0.f;
        }
        out[OFF_DT + (size_t)b * TT + t] = dtv;   // coalesced dword
        sdt[t] = dtv;
    }

    __syncthreads();

    // ---- in-block inclusive scan of sdt ----
    const int s4 = 4 * tid;
    const float4 dvv = *(const float4*)(sdt + s4);   // 16B-aligned LDS read
    const float c0 = dvv.x;
    const float c1 = c0 + dvv.y;
    const float c2 = c1 + dvv.z;
    const float c3 = c2 + dvv.w;
    float s = c3;
    #pragma unroll
    for (int off = 1; off < 64; off <<= 1) {
        const float u = __shfl_up(s, off);
        if (lane >= off) s += u;
    }
    if (lane == 63) wsum[w] = s;   // inclusive wave total

    // ---- wave loss reduce ----
    #pragma unroll
    for (int j = 0; j < 21; ++j) {
        float v = ls[j];
        #pragma unroll
        for (int off = 32; off > 0; off >>= 1) v += __shfl_down(v, off);
        ls[j] = v;   // valid at lane 0
    }
    if (lane == 0) {
        #pragma unroll
        for (int j = 0; j < 21; ++j) lossw[w][j] = ls[j];
    }

    __syncthreads();

    // cross-wave scan offset + t_cumsum stores
    float woff = 0.f;
    #pragma unroll
    for (int i = 0; i < 4; ++i) if (i < w) woff += wsum[i];
    const float excl = woff + (s - c3);   // exclusive prefix before this thread's 4 elems
    st4(out + OFF_TCUM + (size_t)b * TT + s4,
        c0 + excl, c1 + excl, c2 + excl, c3 + excl);

    // loss finalize
    if (tid < 21) {
        const float acc = lossw[0][tid] + lossw[1][tid] + lossw[2][tid] + lossw[3][tid];
        const int which = tid / NDOF, d = tid - which * NDOF;
        const size_t o = (which == 0) ? (size_t)OFF_QDL
                       : (which == 1) ? (size_t)OFF_QDDL : (size_t)OFF_QDDDL;
        out[o + (size_t)b * NDOF + d] = acc;
    }
    if (tid < NDOF) out[OFF_TQL + (size_t)b * NDOF + tid] = 0.0f;  // torque == 0
    if (tid == 0) {
        out[OFF_T + b] = wsum[0] + wsum[1] + wsum[2] + wsum[3];
        // model_loss: one relaxed HW float atomic per block (no fence, no L2 flush)
        float p = 0.f;
        #pragma unroll
        for (int i = 0; i < 4; ++i) {
            #pragma unroll
            for (int j = 0; j < 21; ++j) p += lossw[i][j];
        }
        unsafeAtomicAdd(out + OFF_MODEL, p);   // global_atomic_add_f32, device-coherent
    }
}

extern "C" void kernel_launch(void* const* d_in, const int* in_sizes, int n_in,
                              void* d_out, int out_size, void* d_ws, size_t ws_size,
                              hipStream_t stream) {
    const float* q_cps    = (const float*)d_in[0];
    const float* t_cps    = (const float*)d_in[1];
    const float* Nb       = (const float*)d_in[2];
    const float* dNb      = (const float*)d_in[3];
    const float* ddNb     = (const float*)d_in[4];
    const float* dddNb    = (const float*)d_in[5];
    const float* Ntb      = (const float*)d_in[6];
    const float* dNtb     = (const float*)d_in[7];
    const float* ddNtb    = (const float*)d_in[8];
    const float* qd_lim   = (const float*)d_in[9];
    const float* qdd_lim  = (const float*)d_in[10];
    const float* qddd_lim = (const float*)d_in[11];
    // d_in[12] = torque_limits — unused (torque is identically zero)
    float* out = (float*)d_out;

    // zero the model_loss accumulator each iteration (stream-ordered, graph-legal)
    hipMemsetAsync(out + OFF_MODEL, 0, sizeof(float), stream);

    feas_fused<<<dim3(BB), dim3(256), 0, stream>>>(
        q_cps, t_cps, Nb, dNb, ddNb, dddNb, Ntb, dNtb, ddNtb,
        qd_lim, qdd_lim, qddd_lim, out);
}